// Round 6
// baseline (3386.001 us; speedup 1.0000x reference)
//
#include <hip/hip_runtime.h>

#define NNODES 25600
#define DEG 16
#define BGRAPHS 8
#define NPG (NNODES / BGRAPHS)   // 3200
#define FDIM 7
#define HDIM 300
#define LDIM 100
#define HP 320                   // padded H
#define UVW 640                  // UV row width (U 0..319 | V 320..639)
#define NT1 20                   // GEMM1 N tiles
#define KS1 10                   // GEMM1 K steps
#define NT2 7                    // GEMM2 N tiles (112 cols, >=100 masked)
#define KS2 10                   // GEMM2 K steps
#define H0W 128                  // h0 bf16 padded width
#define SSTR 328                 // proj staging row stride (shorts)

typedef __attribute__((ext_vector_type(8))) short short8;
typedef __attribute__((ext_vector_type(4))) float floatx4;

__device__ __forceinline__ float bf2f(unsigned short h) {
    return __uint_as_float(((unsigned)h) << 16);
}
__device__ __forceinline__ unsigned short f2bf(float f) {   // round-half-up (pack path)
    return (unsigned short)((__float_as_uint(f) + 0x8000u) >> 16);
}
// pack two fp32 (lo,hi) -> one dword of two bf16, round-half-up
__device__ __forceinline__ unsigned packbf2(float lo, float hi) {
    unsigned rl = __float_as_uint(lo) + 0x8000u;
    unsigned rh = __float_as_uint(hi) + 0x8000u;
    return __builtin_amdgcn_perm(rh, rl, 0x07060302);
}

// ---------------------------------------------------------------------------
// B-fragment packing: out[((nt*KS+ks)*64+lane)*8+j] = W[k][n]
// ---------------------------------------------------------------------------
__device__ __forceinline__ unsigned short packB(const float* W, int Kreal, int Nreal,
                                                int KS, int rel)
{
    int j = rel & 7, lane = (rel >> 3) & 63, rem = rel >> 9;
    int ks = rem % KS, nt = rem / KS;
    int k = ks * 32 + ((lane >> 4) << 3) + j;
    int n = nt * 16 + (lane & 15);
    float v = (k < Kreal && n < Nreal) ? W[k * Nreal + n] : 0.f;
    return f2bf(v);
}

// proj effective weights Weff[k][n], n<320 = U part (W1a - W1b), n>=320 = V part (W1b)
__device__ __forceinline__ unsigned short packProjW(const float* W1, int Ksub,
                                                    int KS, int rel)
{
    int j = rel & 7, lane = (rel >> 3) & 63, rem = rel >> 9;
    int ks = rem % KS, nt = rem / KS;
    int k = ks * 32 + ((lane >> 4) << 3) + j;
    int n = nt * 16 + (lane & 15);
    float v = 0.f;
    if (k < Ksub) {
        if (n < HP) { if (n < HDIM) v = W1[k * HDIM + n] - W1[(k + Ksub) * HDIM + n]; }
        else { int m = n - HP; if (m < HDIM) v = W1[(k + Ksub) * HDIM + m]; }
    }
    return f2bf(v);
}

#define S0 102400   // PB2_0
#define S1 102400   // PB2_1
#define S2 35840    // PB3_0
#define S3 35840    // PB3_1
#define S4 81920    // PW1 (40 nt x 4 ks)
#define S5 20480    // PW0 (40 nt x 1 ks)
#define S6 1920     // biases
#define PACK_TOTAL (S0+S1+S2+S3+S4+S5+S6)

__global__ __launch_bounds__(256) void pack_all_kernel(
    const float* __restrict__ l0_W1, const float* __restrict__ l0_b1,
    const float* __restrict__ l0_W2, const float* __restrict__ l0_b2,
    const float* __restrict__ l0_W3,
    const float* __restrict__ l1_W1, const float* __restrict__ l1_b1,
    const float* __restrict__ l1_W2, const float* __restrict__ l1_b2,
    const float* __restrict__ l1_W3,
    unsigned short* __restrict__ PB2_0, unsigned short* __restrict__ PB2_1,
    unsigned short* __restrict__ PB3_0, unsigned short* __restrict__ PB3_1,
    unsigned short* __restrict__ PW1,  unsigned short* __restrict__ PW0,
    float* __restrict__ b2p_0, float* __restrict__ b2p_1,
    float* __restrict__ bp1,   float* __restrict__ bp0)
{
    int idx = blockIdx.x * 256 + threadIdx.x;
    if (idx >= PACK_TOTAL) return;
    if (idx < S0) { PB2_0[idx] = packB(l0_W2, HDIM, HDIM, KS1, idx); return; }
    idx -= S0;
    if (idx < S1) { PB2_1[idx] = packB(l1_W2, HDIM, HDIM, KS1, idx); return; }
    idx -= S1;
    if (idx < S2) { PB3_0[idx] = packB(l0_W3, HDIM, LDIM, KS2, idx); return; }
    idx -= S2;
    if (idx < S3) { PB3_1[idx] = packB(l1_W3, HDIM, LDIM, KS2, idx); return; }
    idx -= S3;
    if (idx < S4) { PW1[idx] = packProjW(l1_W1, LDIM, 4, idx); return; }
    idx -= S4;
    if (idx < S5) { PW0[idx] = packProjW(l0_W1, FDIM, 1, idx); return; }
    idx -= S5;
    if (idx < 320)       { b2p_0[idx] = (idx < HDIM) ? l0_b2[idx] : 0.f; return; }
    if (idx < 640)       { int n = idx - 320; b2p_1[n] = (n < HDIM) ? l1_b2[n] : 0.f; return; }
    if (idx < 1280)      { int n = idx - 640; bp1[n] = (n < HDIM) ? l1_b1[n] : 0.f; return; }
    { int n = idx - 1280; bp0[n] = (n < HDIM) ? l0_b1[n] : 0.f; }
}

// ---------------------------------------------------------------------------
// proj GEMM: A[64 rows] x Weff[K,640] -> UV bf16 [N,640] (bias added, no relu).
// ---------------------------------------------------------------------------
template<int KS, bool A_IS_X>
__global__ __launch_bounds__(256) void proj_gemm_kernel(
    const void* __restrict__ Asrc, const unsigned short* __restrict__ PW,
    const float* __restrict__ bp,
    unsigned short* __restrict__ UV)
{
    __shared__ unsigned short As[4 * KS * 64 * 8];
    __shared__ unsigned short S[64 * SSTR];
    const int t = threadIdx.x;
    const int row0 = blockIdx.x * 64;

    if constexpr (A_IS_X) {
        const float* x = (const float*)Asrc;
        int lane = t & 63, mt = t >> 6;
        int quad = lane >> 4;
        int grow = row0 + mt * 16 + (lane & 15);
        unsigned short oz[8];
#pragma unroll
        for (int j = 0; j < 8; ++j) {
            int k = quad * 8 + j;
            oz[j] = (k < FDIM) ? f2bf(x[grow * FDIM + k]) : (unsigned short)0;
        }
        *(uint4*)(As + t * 8) = *(uint4*)oz;
    } else {
        const unsigned short* h = (const unsigned short*)Asrc;
#pragma unroll
        for (int i = 0; i < 4; ++i) {
            int s = t + 256 * i;
            int lane = s & 63;
            int ks = (s >> 6) % KS;
            int mt = s / (KS * 64);
            int grow = row0 + mt * 16 + (lane & 15);
            int k0 = ks * 32 + ((lane >> 4) << 3);
            *(uint4*)(As + s * 8) = *(const uint4*)(h + (size_t)grow * H0W + k0);
        }
    }
    __syncthreads();

    const int w = t >> 6, lane = t & 63, quad = lane >> 4, l15 = lane & 15;

    for (int g = 0; g < 2; ++g) {
        const int ntb = g * 20 + w * 5;
        floatx4 c[5][4];
#pragma unroll
        for (int i = 0; i < 5; ++i)
#pragma unroll
            for (int mt = 0; mt < 4; ++mt) c[i][mt] = (floatx4){0.f, 0.f, 0.f, 0.f};
#pragma unroll
        for (int ks = 0; ks < KS; ++ks) {
            short8 a[4];
#pragma unroll
            for (int mt = 0; mt < 4; ++mt)
                a[mt] = *(const short8*)(As + ((mt * KS + ks) * 64 + lane) * 8);
#pragma unroll
            for (int i = 0; i < 5; ++i) {
                short8 b = *(const short8*)(PW + (size_t)(((ntb + i) * KS + ks) * 64 + lane) * 8);
#pragma unroll
                for (int mt = 0; mt < 4; ++mt)
                    c[i][mt] = __builtin_amdgcn_mfma_f32_16x16x32_bf16(a[mt], b, c[i][mt], 0, 0, 0);
            }
        }
        __syncthreads();   // prev group's readout complete before overwriting S
#pragma unroll
        for (int i = 0; i < 5; ++i) {
            int colp = (w * 5 + i) * 16 + l15;        // 0..319 group-local
            float bb = bp[g * 320 + colp];
#pragma unroll
            for (int mt = 0; mt < 4; ++mt) {
#pragma unroll
                for (int r = 0; r < 4; ++r) {
                    int row = mt * 16 + quad * 4 + r;
                    S[row * SSTR + colp] = f2bf(c[i][mt][r] + bb);
                }
            }
        }
        __syncthreads();
#pragma unroll
        for (int it = 0; it < 10; ++it) {
            int s = t + 256 * it;
            int row = s / 40, c4 = s - row * 40;
            uint4 v = *(const uint4*)(S + row * SSTR + c4 * 8);
            *(uint4*)(UV + (size_t)(row0 + row) * UVW + g * 320 + c4 * 8) = v;
        }
    }
}

// ---------------------------------------------------------------------------
// Fused edge MLP + segment-max. Block = 4 nodes (M=64), 256 threads / 4 waves.
// SINGLE 20480 B LDS buffer, K-chunked through both GEMMs:
//   Z1 K-half h (160 cols): build -> GEMM1 partial (C1 in AGPRs)   x2
//   Z2 K-chunk c (160 cols): scatter (waves 2c,2c+1) -> GEMM2 partial x2
// 20480 B x 8 blocks = 160 KiB exactly -> 8 blocks/CU (vs 3 before).
// Accumulation order identical to the monolithic version (bit-identical).
// ---------------------------------------------------------------------------
template<bool OUT_BF16>
__global__ __launch_bounds__(256, 8) void edge_mfma_kernel(
    const unsigned short* __restrict__ UV,
    const int* __restrict__ src,
    const unsigned short* __restrict__ PB2, const float* __restrict__ b2p,
    const unsigned short* __restrict__ PB3, const float* __restrict__ b3,
    void* __restrict__ hout)
{
    __shared__ unsigned short Zs[4 * 5 * 64 * 8];   // 20480 B, Z1-half then Z2-chunk

    const int t = threadIdx.x;
    const int node0 = blockIdx.x * 4;
    const int lane = t & 63;
    const int w = t >> 6;
    const int quad = lane >> 4;
    const int l15 = lane & 15;
    const int slane = lane ^ ((lane & 0x30) >> 3);   // sigma(lane) for Z1 reads

    // Z1-build lane mapping (64B-coalesced gather + swizzled LDS dest)
    const int row16 = lane >> 2;          // 0..15
    const int part  = lane & 3;           // 0..3
    const int fl    = row16 + 16 * part;  // A-frag lane
    const int phys  = fl ^ (part << 1);   // sigma(fl)

    // GEMM1 accumulators (full N slice, both K passes)
    floatx4 c1[5][4];
#pragma unroll
    for (int i = 0; i < 5; ++i)
#pragma unroll
        for (int mt = 0; mt < 4; ++mt) c1[i][mt] = (floatx4){0.f, 0.f, 0.f, 0.f};

    // ---- GEMM1 over two K-halves through the single buffer ----
#pragma unroll
    for (int h = 0; h < 2; ++h) {
        // build Z1 half h: 1280 slots, 5 per thread
#pragma unroll
        for (int i = 0; i < 5; ++i) {
            int s = t + 256 * i;
            int ks = (s >> 6) % 5;            // local ks
            int mt = s / 320;                 // 0..3
            int m = mt * 16 + row16;
            int k0 = (h * 5 + ks) * 32 + part * 8;
            int srcn = src[node0 * 16 + m];
            uint4 ud = *(const uint4*)(UV + (size_t)(node0 + mt) * UVW + k0);
            uint4 vd = *(const uint4*)(UV + (size_t)srcn * UVW + HP + k0);
            unsigned o[4];
            const unsigned* up = (const unsigned*)&ud;
            const unsigned* vp = (const unsigned*)&vd;
#pragma unroll
            for (int d = 0; d < 4; ++d) {
                float ul = __uint_as_float(up[d] << 16);
                float uh = __uint_as_float(up[d] & 0xFFFF0000u);
                float vl = __uint_as_float(vp[d] << 16);
                float vh = __uint_as_float(vp[d] & 0xFFFF0000u);
                float sl = fmaxf(ul + vl, 0.f);
                float sh = fmaxf(uh + vh, 0.f);
                o[d] = packbf2(sl, sh);
            }
            *(uint4*)(Zs + ((mt * 5 + ks) * 64 + phys) * 8) = *(uint4*)o;
        }
        __syncthreads();
        // GEMM1 partial: ks 0..4 of this half, wave owns nt = w*5..w*5+4
#pragma unroll
        for (int ks = 0; ks < 5; ++ks) {
            short8 a[4];
#pragma unroll
            for (int mt = 0; mt < 4; ++mt)
                a[mt] = *(const short8*)(Zs + ((mt * 5 + ks) * 64 + slane) * 8);
#pragma unroll
            for (int i = 0; i < 5; ++i) {
                short8 b = *(const short8*)(PB2 + (size_t)(((w * 5 + i) * KS1 + h * 5 + ks) * 64 + lane) * 8);
#pragma unroll
                for (int mt = 0; mt < 4; ++mt)
                    c1[i][mt] = __builtin_amdgcn_mfma_f32_16x16x32_bf16(a[mt], b, c1[i][mt], 0, 0, 0);
            }
        }
        __syncthreads();   // all waves done with this half before rebuild/reuse
    }

    // ---- GEMM2 over two K-chunks through the same buffer ----
    const int cnt2 = (w < 3) ? 2 : 1;
    floatx4 c2[4][2];
#pragma unroll
    for (int mt = 0; mt < 4; ++mt)
#pragma unroll
        for (int i = 0; i < 2; ++i) c2[mt][i] = (floatx4){0.f, 0.f, 0.f, 0.f};

#pragma unroll
    for (int c = 0; c < 2; ++c) {
        // scatter Z2 chunk c: wave w's cols are 80w..80w+79 -> chunk = w>>1
        if ((w >> 1) == c) {
#pragma unroll
            for (int i = 0; i < 5; ++i) {
                int col = (w * 5 + i) * 16 + l15;        // global col 0..319
                float b2v = b2p[col];
                int kc = col - c * 160;                  // 0..159 chunk-local
                int slotbase = (kc >> 5) * 64 + (((kc >> 3) & 3) << 4) + quad * 4;
                int j = kc & 7;
#pragma unroll
                for (int mt = 0; mt < 4; ++mt) {
#pragma unroll
                    for (int r = 0; r < 4; ++r) {
                        float v = fmaxf(c1[i][mt][r] + b2v, 0.f);
                        Zs[(mt * 5 * 64 + slotbase + r) * 8 + j] = f2bf(v);
                    }
                }
            }
        }
        __syncthreads();
        // GEMM2 partial: ks 0..4 of chunk c, wave owns nt2 {w*2, w*2+1}
#pragma unroll
        for (int ks = 0; ks < 5; ++ks) {
            int ksg = c * 5 + ks;
            short8 a[4];
#pragma unroll
            for (int mt = 0; mt < 4; ++mt)
                a[mt] = *(const short8*)(Zs + ((mt * 5 + ks) * 64 + lane) * 8);
#pragma unroll
            for (int i = 0; i < 2; ++i) {
                if (i < cnt2) {
                    short8 b = *(const short8*)(PB3 + (size_t)(((w * 2 + i) * KS2 + ksg) * 64 + lane) * 8);
#pragma unroll
                    for (int mt = 0; mt < 4; ++mt)
                        c2[mt][i] = __builtin_amdgcn_mfma_f32_16x16x32_bf16(a[mt], b, c2[mt][i], 0, 0, 0);
                }
            }
        }
        if (c == 0) __syncthreads();   // chunk-0 reads done before chunk-1 scatter
    }

    // ---- epilogue: max over 16 edge rows, +b3, relu, store ----
#pragma unroll
    for (int mt = 0; mt < 4; ++mt) {
        int node = node0 + mt;
#pragma unroll
        for (int i = 0; i < 2; ++i) {
            if (i < cnt2) {
                int col = (w * 2 + i) * 16 + l15;
                floatx4 a = c2[mt][i];
                float mx = fmaxf(fmaxf(a[0], a[1]), fmaxf(a[2], a[3]));
                mx = fmaxf(mx, __shfl_xor(mx, 16, 64));
                mx = fmaxf(mx, __shfl_xor(mx, 32, 64));
                if (quad == 0) {
                    if (OUT_BF16) {
                        unsigned short val = 0;
                        if (col < LDIM) val = f2bf(fmaxf(mx + b3[col], 0.f));
                        ((unsigned short*)hout)[(size_t)node * H0W + col] = val;
                    } else {
                        if (col < LDIM)
                            ((float*)hout)[(size_t)node * LDIM + col] = fmaxf(mx + b3[col], 0.f);
                    }
                }
            }
        }
        if (OUT_BF16 && w == 3 && quad == 0)
            ((unsigned short*)hout)[(size_t)node * H0W + 112 + l15] = 0;
    }
}

// ---------------------------------------------------------------------------
__global__ __launch_bounds__(128) void pool1_kernel(
    const float* __restrict__ h, float* __restrict__ part)
{
    int g = blockIdx.x / 25;
    int sl = blockIdx.x % 25;
    int t = threadIdx.x;
    int base = g * NPG + sl * 128;
    if (t < LDIM) {
        float s = 0.f, mx = -1e30f;
        for (int i = 0; i < 128; ++i) {
            float v = h[(size_t)(base + i) * LDIM + t];
            s += v;
            mx = fmaxf(mx, v);
        }
        part[(size_t)blockIdx.x * 200 + t] = s;
        part[(size_t)blockIdx.x * 200 + 100 + t] = mx;
    }
}

__global__ __launch_bounds__(256) void final_kernel(
    const float* __restrict__ part,
    const float* __restrict__ W1, const float* __restrict__ b1,
    const float* __restrict__ W2, const float* __restrict__ b2,
    const float* __restrict__ W3, const float* __restrict__ b3,
    float* __restrict__ out)
{
    __shared__ float P[BGRAPHS][3 * LDIM];
    __shared__ float T1[BGRAPHS][LDIM];
    __shared__ float T2[BGRAPHS][LDIM];
    int t = threadIdx.x;
    for (int i = t; i < BGRAPHS * LDIM; i += 256) {
        int g = i / LDIM, f = i - (i / LDIM) * LDIM;
        float s = 0.f, mx = -1e30f;
        for (int sl = 0; sl < 25; ++sl) {
            s += part[(size_t)(g * 25 + sl) * 200 + f];
            mx = fmaxf(mx, part[(size_t)(g * 25 + sl) * 200 + 100 + f]);
        }
        P[g][f] = s;
        P[g][LDIM + f] = s * (1.0f / NPG);
        P[g][2 * LDIM + f] = mx;
    }
    __syncthreads();
    for (int i = t; i < BGRAPHS * LDIM; i += 256) {
        int g = i / LDIM, c = i - (i / LDIM) * LDIM;
        float a = b1[c];
        for (int k = 0; k < 3 * LDIM; ++k) a = fmaf(P[g][k], W1[k * LDIM + c], a);
        T1[g][c] = fmaxf(a, 0.f);
    }
    __syncthreads();
    for (int i = t; i < BGRAPHS * LDIM; i += 256) {
        int g = i / LDIM, c = i - (i / LDIM) * LDIM;
        float a = b2[c];
        for (int k = 0; k < LDIM; ++k) a = fmaf(T1[g][k], W2[k * LDIM + c], a);
        T2[g][c] = fmaxf(a, 0.f);
    }
    __syncthreads();
    if (t < BGRAPHS) {
        float a = b3[0];
        for (int k = 0; k < LDIM; ++k) a = fmaf(T2[t][k], W3[k], a);
        out[t] = a;
    }
}

// ---------------------------------------------------------------------------
extern "C" void kernel_launch(void* const* d_in, const int* in_sizes, int n_in,
                              void* d_out, int out_size, void* d_ws, size_t ws_size,
                              hipStream_t stream)
{
    const float* x      = (const float*)d_in[0];
    const int*   src    = (const int*)d_in[1];
    const float* l0_W1  = (const float*)d_in[3];
    const float* l0_b1  = (const float*)d_in[4];
    const float* l0_W2  = (const float*)d_in[5];
    const float* l0_b2  = (const float*)d_in[6];
    const float* l0_W3  = (const float*)d_in[7];
    const float* l0_b3  = (const float*)d_in[8];
    const float* l1_W1  = (const float*)d_in[9];
    const float* l1_b1  = (const float*)d_in[10];
    const float* l1_W2  = (const float*)d_in[11];
    const float* l1_b2  = (const float*)d_in[12];
    const float* l1_W3  = (const float*)d_in[13];
    const float* l1_b3  = (const float*)d_in[14];
    const float* lin_W1 = (const float*)d_in[15];
    const float* lin_b1 = (const float*)d_in[16];
    const float* lin_W2 = (const float*)d_in[17];
    const float* lin_b2 = (const float*)d_in[18];
    const float* lin_W3 = (const float*)d_in[19];
    const float* lin_b3 = (const float*)d_in[20];
    float* out = (float*)d_out;

    char* p = (char*)d_ws;
    unsigned short* UV    = (unsigned short*)p;  p += (size_t)NNODES * UVW * 2;     // 32.77 MB
    unsigned short* h0b   = (unsigned short*)p;  p += (size_t)NNODES * H0W * 2;     // 6.55 MB
    float* h1             = (float*)p;           p += (size_t)NNODES * LDIM * 4;    // 10.24 MB
    unsigned short* PB2_0 = (unsigned short*)p;  p += (size_t)S0 * 2;
    unsigned short* PB2_1 = (unsigned short*)p;  p += (size_t)S1 * 2;
    unsigned short* PB3_0 = (unsigned short*)p;  p += (size_t)S2 * 2;
    unsigned short* PB3_1 = (unsigned short*)p;  p += (size_t)S3 * 2;
    unsigned short* PW1   = (unsigned short*)p;  p += (size_t)S4 * 2;
    unsigned short* PW0   = (unsigned short*)p;  p += (size_t)S5 * 2;
    float* b2p_0          = (float*)p;           p += HP * 4;
    float* b2p_1          = (float*)p;           p += HP * 4;
    float* bp1            = (float*)p;           p += 640 * 4;
    float* bp0            = (float*)p;           p += 640 * 4;
    float* part           = (float*)p;           p += (size_t)200 * 200 * 4;

    pack_all_kernel<<<(PACK_TOTAL + 255) / 256, 256, 0, stream>>>(
        l0_W1, l0_b1, l0_W2, l0_b2, l0_W3,
        l1_W1, l1_b1, l1_W2, l1_b2, l1_W3,
        PB2_0, PB2_1, PB3_0, PB3_1, PW1, PW0, b2p_0, b2p_1, bp1, bp0);

    // layer 0
    proj_gemm_kernel<1, true><<<NNODES / 64, 256, 0, stream>>>(x, PW0, bp0, UV);
    edge_mfma_kernel<true><<<NNODES / 4, 256, 0, stream>>>(UV, src, PB2_0, b2p_0, PB3_0, l0_b3, h0b);
    // layer 1
    proj_gemm_kernel<4, false><<<NNODES / 64, 256, 0, stream>>>(h0b, PW1, bp1, UV);
    edge_mfma_kernel<false><<<NNODES / 4, 256, 0, stream>>>(UV, src, PB2_1, b2p_1, PB3_1, l1_b3, h1);
    // pooling + head
    pool1_kernel<<<200, 128, 0, stream>>>(h1, part);
    final_kernel<<<1, 256, 0, stream>>>(part, lin_W1, lin_b1, lin_W2, lin_b2, lin_W3, lin_b3, out);
}

// Round 7
// 444.137 us; speedup vs baseline: 7.6238x; 7.6238x over previous
//
#include <hip/hip_runtime.h>

#define NNODES 25600
#define DEG 16
#define BGRAPHS 8
#define NPG (NNODES / BGRAPHS)   // 3200
#define FDIM 7
#define HDIM 300
#define LDIM 100
#define HP 320                   // padded H
#define UVW 640                  // UV row width (U 0..319 | V 320..639)
#define NT1 20                   // GEMM1 N tiles
#define KS1 10                   // GEMM1 K steps
#define NT2 7                    // GEMM2 N tiles (112 cols, >=100 masked)
#define KS2 10                   // GEMM2 K steps
#define H0W 128                  // h0 bf16 padded width
#define SSTR 328                 // proj staging row stride (shorts)

typedef __attribute__((ext_vector_type(8))) short short8;
typedef __attribute__((ext_vector_type(4))) float floatx4;

__device__ __forceinline__ float bf2f(unsigned short h) {
    return __uint_as_float(((unsigned)h) << 16);
}
__device__ __forceinline__ unsigned short f2bf(float f) {   // round-half-up (pack path)
    return (unsigned short)((__float_as_uint(f) + 0x8000u) >> 16);
}
// pack two fp32 (lo,hi) -> one dword of two bf16, round-half-up
__device__ __forceinline__ unsigned packbf2(float lo, float hi) {
    unsigned rl = __float_as_uint(lo) + 0x8000u;
    unsigned rh = __float_as_uint(hi) + 0x8000u;
    return __builtin_amdgcn_perm(rh, rl, 0x07060302);
}

// ---------------------------------------------------------------------------
// B-fragment packing: out[((nt*KS+ks)*64+lane)*8+j] = W[k][n]
// ---------------------------------------------------------------------------
__device__ __forceinline__ unsigned short packB(const float* W, int Kreal, int Nreal,
                                                int KS, int rel)
{
    int j = rel & 7, lane = (rel >> 3) & 63, rem = rel >> 9;
    int ks = rem % KS, nt = rem / KS;
    int k = ks * 32 + ((lane >> 4) << 3) + j;
    int n = nt * 16 + (lane & 15);
    float v = (k < Kreal && n < Nreal) ? W[k * Nreal + n] : 0.f;
    return f2bf(v);
}

// proj effective weights Weff[k][n], n<320 = U part (W1a - W1b), n>=320 = V part (W1b)
__device__ __forceinline__ unsigned short packProjW(const float* W1, int Ksub,
                                                    int KS, int rel)
{
    int j = rel & 7, lane = (rel >> 3) & 63, rem = rel >> 9;
    int ks = rem % KS, nt = rem / KS;
    int k = ks * 32 + ((lane >> 4) << 3) + j;
    int n = nt * 16 + (lane & 15);
    float v = 0.f;
    if (k < Ksub) {
        if (n < HP) { if (n < HDIM) v = W1[k * HDIM + n] - W1[(k + Ksub) * HDIM + n]; }
        else { int m = n - HP; if (m < HDIM) v = W1[(k + Ksub) * HDIM + m]; }
    }
    return f2bf(v);
}

#define S0 102400   // PB2_0
#define S1 102400   // PB2_1
#define S2 35840    // PB3_0
#define S3 35840    // PB3_1
#define S4 81920    // PW1 (40 nt x 4 ks)
#define S5 20480    // PW0 (40 nt x 1 ks)
#define S6 1920     // biases
#define PACK_TOTAL (S0+S1+S2+S3+S4+S5+S6)

__global__ __launch_bounds__(256) void pack_all_kernel(
    const float* __restrict__ l0_W1, const float* __restrict__ l0_b1,
    const float* __restrict__ l0_W2, const float* __restrict__ l0_b2,
    const float* __restrict__ l0_W3,
    const float* __restrict__ l1_W1, const float* __restrict__ l1_b1,
    const float* __restrict__ l1_W2, const float* __restrict__ l1_b2,
    const float* __restrict__ l1_W3,
    unsigned short* __restrict__ PB2_0, unsigned short* __restrict__ PB2_1,
    unsigned short* __restrict__ PB3_0, unsigned short* __restrict__ PB3_1,
    unsigned short* __restrict__ PW1,  unsigned short* __restrict__ PW0,
    float* __restrict__ b2p_0, float* __restrict__ b2p_1,
    float* __restrict__ bp1,   float* __restrict__ bp0)
{
    int idx = blockIdx.x * 256 + threadIdx.x;
    if (idx >= PACK_TOTAL) return;
    if (idx < S0) { PB2_0[idx] = packB(l0_W2, HDIM, HDIM, KS1, idx); return; }
    idx -= S0;
    if (idx < S1) { PB2_1[idx] = packB(l1_W2, HDIM, HDIM, KS1, idx); return; }
    idx -= S1;
    if (idx < S2) { PB3_0[idx] = packB(l0_W3, HDIM, LDIM, KS2, idx); return; }
    idx -= S2;
    if (idx < S3) { PB3_1[idx] = packB(l1_W3, HDIM, LDIM, KS2, idx); return; }
    idx -= S3;
    if (idx < S4) { PW1[idx] = packProjW(l1_W1, LDIM, 4, idx); return; }
    idx -= S4;
    if (idx < S5) { PW0[idx] = packProjW(l0_W1, FDIM, 1, idx); return; }
    idx -= S5;
    if (idx < 320)       { b2p_0[idx] = (idx < HDIM) ? l0_b2[idx] : 0.f; return; }
    if (idx < 640)       { int n = idx - 320; b2p_1[n] = (n < HDIM) ? l1_b2[n] : 0.f; return; }
    if (idx < 1280)      { int n = idx - 640; bp1[n] = (n < HDIM) ? l1_b1[n] : 0.f; return; }
    { int n = idx - 1280; bp0[n] = (n < HDIM) ? l0_b1[n] : 0.f; }
}

// ---------------------------------------------------------------------------
// proj GEMM: A[64 rows] x Weff[K,640] -> UV bf16 [N,640] (bias added, no relu).
// ---------------------------------------------------------------------------
template<int KS, bool A_IS_X>
__global__ __launch_bounds__(256) void proj_gemm_kernel(
    const void* __restrict__ Asrc, const unsigned short* __restrict__ PW,
    const float* __restrict__ bp,
    unsigned short* __restrict__ UV)
{
    __shared__ unsigned short As[4 * KS * 64 * 8];
    __shared__ unsigned short S[64 * SSTR];
    const int t = threadIdx.x;
    const int row0 = blockIdx.x * 64;

    if constexpr (A_IS_X) {
        const float* x = (const float*)Asrc;
        int lane = t & 63, mt = t >> 6;
        int quad = lane >> 4;
        int grow = row0 + mt * 16 + (lane & 15);
        unsigned short oz[8];
#pragma unroll
        for (int j = 0; j < 8; ++j) {
            int k = quad * 8 + j;
            oz[j] = (k < FDIM) ? f2bf(x[grow * FDIM + k]) : (unsigned short)0;
        }
        *(uint4*)(As + t * 8) = *(uint4*)oz;
    } else {
        const unsigned short* h = (const unsigned short*)Asrc;
#pragma unroll
        for (int i = 0; i < 4; ++i) {
            int s = t + 256 * i;
            int lane = s & 63;
            int ks = (s >> 6) % KS;
            int mt = s / (KS * 64);
            int grow = row0 + mt * 16 + (lane & 15);
            int k0 = ks * 32 + ((lane >> 4) << 3);
            *(uint4*)(As + s * 8) = *(const uint4*)(h + (size_t)grow * H0W + k0);
        }
    }
    __syncthreads();

    const int w = t >> 6, lane = t & 63, quad = lane >> 4, l15 = lane & 15;

    for (int g = 0; g < 2; ++g) {
        const int ntb = g * 20 + w * 5;
        floatx4 c[5][4];
#pragma unroll
        for (int i = 0; i < 5; ++i)
#pragma unroll
            for (int mt = 0; mt < 4; ++mt) c[i][mt] = (floatx4){0.f, 0.f, 0.f, 0.f};
#pragma unroll
        for (int ks = 0; ks < KS; ++ks) {
            short8 a[4];
#pragma unroll
            for (int mt = 0; mt < 4; ++mt)
                a[mt] = *(const short8*)(As + ((mt * KS + ks) * 64 + lane) * 8);
#pragma unroll
            for (int i = 0; i < 5; ++i) {
                short8 b = *(const short8*)(PW + (size_t)(((ntb + i) * KS + ks) * 64 + lane) * 8);
#pragma unroll
                for (int mt = 0; mt < 4; ++mt)
                    c[i][mt] = __builtin_amdgcn_mfma_f32_16x16x32_bf16(a[mt], b, c[i][mt], 0, 0, 0);
            }
        }
        __syncthreads();   // prev group's readout complete before overwriting S
#pragma unroll
        for (int i = 0; i < 5; ++i) {
            int colp = (w * 5 + i) * 16 + l15;        // 0..319 group-local
            float bb = bp[g * 320 + colp];
#pragma unroll
            for (int mt = 0; mt < 4; ++mt) {
#pragma unroll
                for (int r = 0; r < 4; ++r) {
                    int row = mt * 16 + quad * 4 + r;
                    S[row * SSTR + colp] = f2bf(c[i][mt][r] + bb);
                }
            }
        }
        __syncthreads();
#pragma unroll
        for (int it = 0; it < 10; ++it) {
            int s = t + 256 * it;
            int row = s / 40, c4 = s - row * 40;
            uint4 v = *(const uint4*)(S + row * SSTR + c4 * 8);
            *(uint4*)(UV + (size_t)(row0 + row) * UVW + g * 320 + c4 * 8) = v;
        }
    }
}

// ---------------------------------------------------------------------------
// Fused edge MLP + segment-max. Block = 4 nodes (M=64), 512 threads / 8 waves.
// Same single 40 KB LDS buffer & phase order as the 196us R5 version, but
// accumulators split across 8 waves instead of 4:
//   GEMM1: wave owns {3,3,3,3,2,2,2,2} ntiles -> C1 regs <= 48
//   GEMM2: wave w<7 owns 1 ntile          -> C2 regs = 16
// Total live regs ~115 -> fits 4 waves/EU (2 blocks/CU, 16 waves/CU).
// ---------------------------------------------------------------------------
template<bool OUT_BF16>
__global__ __launch_bounds__(512, 4) void edge_mfma_kernel(
    const unsigned short* __restrict__ UV,
    const int* __restrict__ src,
    const unsigned short* __restrict__ PB2, const float* __restrict__ b2p,
    const unsigned short* __restrict__ PB3, const float* __restrict__ b3,
    void* __restrict__ hout)
{
    __shared__ unsigned short Zs[4 * KS1 * 64 * 8];   // 40960 B, Z1 then Z2

    const int t = threadIdx.x;
    const int node0 = blockIdx.x * 4;
    const int lane = t & 63;
    const int w = t >> 6;                 // 0..7
    const int quad = lane >> 4;
    const int l15 = lane & 15;
    const int slane = lane ^ ((lane & 0x30) >> 3);   // sigma(lane) for Z1 reads

    // Z1-build lane mapping (64B-coalesced gather + swizzled LDS dest)
    const int row16 = lane >> 2;          // 0..15
    const int part  = lane & 3;           // 0..3
    const int fl    = row16 + 16 * part;  // A-frag lane
    const int phys  = fl ^ (part << 1);   // sigma(fl)

    // ---- Z1 build: 2560 slots, 5 per thread ----
#pragma unroll
    for (int i = 0; i < 5; ++i) {
        int s = t + 512 * i;
        int ks = (s >> 6) % KS1;
        int mt = s / (KS1 * 64);
        int m = mt * 16 + row16;
        int k0 = ks * 32 + part * 8;
        int srcn = src[node0 * 16 + m];
        uint4 ud = *(const uint4*)(UV + (size_t)(node0 + mt) * UVW + k0);
        uint4 vd = *(const uint4*)(UV + (size_t)srcn * UVW + HP + k0);
        unsigned o[4];
        const unsigned* up = (const unsigned*)&ud;
        const unsigned* vp = (const unsigned*)&vd;
#pragma unroll
        for (int d = 0; d < 4; ++d) {
            float ul = __uint_as_float(up[d] << 16);
            float uh = __uint_as_float(up[d] & 0xFFFF0000u);
            float vl = __uint_as_float(vp[d] << 16);
            float vh = __uint_as_float(vp[d] & 0xFFFF0000u);
            float sl = fmaxf(ul + vl, 0.f);
            float sh = fmaxf(uh + vh, 0.f);
            o[d] = packbf2(sl, sh);
        }
        *(uint4*)(Zs + ((mt * KS1 + ks) * 64 + phys) * 8) = *(uint4*)o;
    }
    __syncthreads();

    // ---- GEMM1: wave owns cnt1 ntiles starting at base1, all 4 mt ----
    const int cnt1  = (w < 4) ? 3 : 2;
    const int base1 = (w < 4) ? 3 * w : 12 + 2 * (w - 4);
    floatx4 c1[3][4];
#pragma unroll
    for (int i = 0; i < 3; ++i)
#pragma unroll
        for (int mt = 0; mt < 4; ++mt) c1[i][mt] = (floatx4){0.f, 0.f, 0.f, 0.f};
    for (int ks = 0; ks < KS1; ++ks) {
        short8 a[4];
#pragma unroll
        for (int mt = 0; mt < 4; ++mt)
            a[mt] = *(const short8*)(Zs + ((mt * KS1 + ks) * 64 + slane) * 8);
#pragma unroll
        for (int i = 0; i < 3; ++i) {
            if (i < cnt1) {
                short8 b = *(const short8*)(PB2 + (size_t)(((base1 + i) * KS1 + ks) * 64 + lane) * 8);
#pragma unroll
                for (int mt = 0; mt < 4; ++mt)
                    c1[i][mt] = __builtin_amdgcn_mfma_f32_16x16x32_bf16(a[mt], b, c1[i][mt], 0, 0, 0);
            }
        }
    }
    __syncthreads();   // all waves done reading Z1

    // ---- Z2 scatter into Zs (A-frag order, identity), +b2, relu ----
#pragma unroll
    for (int i = 0; i < 3; ++i) {
        if (i < cnt1) {
            int col = (base1 + i) * 16 + l15;            // 0..319
            float b2v = b2p[col];
            int slotbase = (col >> 5) * 64 + (((col >> 3) & 3) << 4) + quad * 4;
            int j = col & 7;
#pragma unroll
            for (int mt = 0; mt < 4; ++mt) {
#pragma unroll
                for (int r = 0; r < 4; ++r) {
                    float v = fmaxf(c1[i][mt][r] + b2v, 0.f);
                    Zs[(mt * KS1 * 64 + slotbase + r) * 8 + j] = f2bf(v);
                }
            }
        }
    }
    __syncthreads();

    // ---- GEMM2: wave w<7 owns ntile w, all 4 mt ----
    floatx4 c2[4];
#pragma unroll
    for (int mt = 0; mt < 4; ++mt) c2[mt] = (floatx4){0.f, 0.f, 0.f, 0.f};
    if (w < NT2) {
        for (int ks = 0; ks < KS2; ++ks) {
            short8 a[4];
#pragma unroll
            for (int mt = 0; mt < 4; ++mt)
                a[mt] = *(const short8*)(Zs + ((mt * KS2 + ks) * 64 + lane) * 8);
            short8 b = *(const short8*)(PB3 + (size_t)((w * KS2 + ks) * 64 + lane) * 8);
#pragma unroll
            for (int mt = 0; mt < 4; ++mt)
                c2[mt] = __builtin_amdgcn_mfma_f32_16x16x32_bf16(a[mt], b, c2[mt], 0, 0, 0);
        }
    }

    // ---- epilogue: max over 16 edge rows, +b3, relu, store ----
#pragma unroll
    for (int mt = 0; mt < 4; ++mt) {
        int node = node0 + mt;
        if (w < NT2) {
            int col = w * 16 + l15;
            floatx4 a = c2[mt];
            float mx = fmaxf(fmaxf(a[0], a[1]), fmaxf(a[2], a[3]));
            mx = fmaxf(mx, __shfl_xor(mx, 16, 64));
            mx = fmaxf(mx, __shfl_xor(mx, 32, 64));
            if (quad == 0) {
                if (OUT_BF16) {
                    unsigned short val = 0;
                    if (col < LDIM) val = f2bf(fmaxf(mx + b3[col], 0.f));
                    ((unsigned short*)hout)[(size_t)node * H0W + col] = val;
                } else {
                    if (col < LDIM)
                        ((float*)hout)[(size_t)node * LDIM + col] = fmaxf(mx + b3[col], 0.f);
                }
            }
        }
        if (OUT_BF16 && w == 7 && quad == 0)     // pad cols 112..127
            ((unsigned short*)hout)[(size_t)node * H0W + 112 + l15] = 0;
    }
}

// ---------------------------------------------------------------------------
__global__ __launch_bounds__(128) void pool1_kernel(
    const float* __restrict__ h, float* __restrict__ part)
{
    int g = blockIdx.x / 25;
    int sl = blockIdx.x % 25;
    int t = threadIdx.x;
    int base = g * NPG + sl * 128;
    if (t < LDIM) {
        float s = 0.f, mx = -1e30f;
        for (int i = 0; i < 128; ++i) {
            float v = h[(size_t)(base + i) * LDIM + t];
            s += v;
            mx = fmaxf(mx, v);
        }
        part[(size_t)blockIdx.x * 200 + t] = s;
        part[(size_t)blockIdx.x * 200 + 100 + t] = mx;
    }
}

__global__ __launch_bounds__(256) void final_kernel(
    const float* __restrict__ part,
    const float* __restrict__ W1, const float* __restrict__ b1,
    const float* __restrict__ W2, const float* __restrict__ b2,
    const float* __restrict__ W3, const float* __restrict__ b3,
    float* __restrict__ out)
{
    __shared__ float P[BGRAPHS][3 * LDIM];
    __shared__ float T1[BGRAPHS][LDIM];
    __shared__ float T2[BGRAPHS][LDIM];
    int t = threadIdx.x;
    for (int i = t; i < BGRAPHS * LDIM; i += 256) {
        int g = i / LDIM, f = i - (i / LDIM) * LDIM;
        float s = 0.f, mx = -1e30f;
        for (int sl = 0; sl < 25; ++sl) {
            s += part[(size_t)(g * 25 + sl) * 200 + f];
            mx = fmaxf(mx, part[(size_t)(g * 25 + sl) * 200 + 100 + f]);
        }
        P[g][f] = s;
        P[g][LDIM + f] = s * (1.0f / NPG);
        P[g][2 * LDIM + f] = mx;
    }
    __syncthreads();
    for (int i = t; i < BGRAPHS * LDIM; i += 256) {
        int g = i / LDIM, c = i - (i / LDIM) * LDIM;
        float a = b1[c];
        for (int k = 0; k < 3 * LDIM; ++k) a = fmaf(P[g][k], W1[k * LDIM + c], a);
        T1[g][c] = fmaxf(a, 0.f);
    }
    __syncthreads();
    for (int i = t; i < BGRAPHS * LDIM; i += 256) {
        int g = i / LDIM, c = i - (i / LDIM) * LDIM;
        float a = b2[c];
        for (int k = 0; k < LDIM; ++k) a = fmaf(T1[g][k], W2[k * LDIM + c], a);
        T2[g][c] = fmaxf(a, 0.f);
    }
    __syncthreads();
    if (t < BGRAPHS) {
        float a = b3[0];
        for (int k = 0; k < LDIM; ++k) a = fmaf(T2[t][k], W3[k], a);
        out[t] = a;
    }
}

// ---------------------------------------------------------------------------
extern "C" void kernel_launch(void* const* d_in, const int* in_sizes, int n_in,
                              void* d_out, int out_size, void* d_ws, size_t ws_size,
                              hipStream_t stream)
{
    const float* x      = (const float*)d_in[0];
    const int*   src    = (const int*)d_in[1];
    const float* l0_W1  = (const float*)d_in[3];
    const float* l0_b1  = (const float*)d_in[4];
    const float* l0_W2  = (const float*)d_in[5];
    const float* l0_b2  = (const float*)d_in[6];
    const float* l0_W3  = (const float*)d_in[7];
    const float* l0_b3  = (const float*)d_in[8];
    const float* l1_W1  = (const float*)d_in[9];
    const float* l1_b1  = (const float*)d_in[10];
    const float* l1_W2  = (const float*)d_in[11];
    const float* l1_b2  = (const float*)d_in[12];
    const float* l1_W3  = (const float*)d_in[13];
    const float* l1_b3  = (const float*)d_in[14];
    const float* lin_W1 = (const float*)d_in[15];
    const float* lin_b1 = (const float*)d_in[16];
    const float* lin_W2 = (const float*)d_in[17];
    const float* lin_b2 = (const float*)d_in[18];
    const float* lin_W3 = (const float*)d_in[19];
    const float* lin_b3 = (const float*)d_in[20];
    float* out = (float*)d_out;

    char* p = (char*)d_ws;
    unsigned short* UV    = (unsigned short*)p;  p += (size_t)NNODES * UVW * 2;     // 32.77 MB
    unsigned short* h0b   = (unsigned short*)p;  p += (size_t)NNODES * H0W * 2;     // 6.55 MB
    float* h1             = (float*)p;           p += (size_t)NNODES * LDIM * 4;    // 10.24 MB
    unsigned short* PB2_0 = (unsigned short*)p;  p += (size_t)S0 * 2;
    unsigned short* PB2_1 = (unsigned short*)p;  p += (size_t)S1 * 2;
    unsigned short* PB3_0 = (unsigned short*)p;  p += (size_t)S2 * 2;
    unsigned short* PB3_1 = (unsigned short*)p;  p += (size_t)S3 * 2;
    unsigned short* PW1   = (unsigned short*)p;  p += (size_t)S4 * 2;
    unsigned short* PW0   = (unsigned short*)p;  p += (size_t)S5 * 2;
    float* b2p_0          = (float*)p;           p += HP * 4;
    float* b2p_1          = (float*)p;           p += HP * 4;
    float* bp1            = (float*)p;           p += 640 * 4;
    float* bp0            = (float*)p;           p += 640 * 4;
    float* part           = (float*)p;           p += (size_t)200 * 200 * 4;

    pack_all_kernel<<<(PACK_TOTAL + 255) / 256, 256, 0, stream>>>(
        l0_W1, l0_b1, l0_W2, l0_b2, l0_W3,
        l1_W1, l1_b1, l1_W2, l1_b2, l1_W3,
        PB2_0, PB2_1, PB3_0, PB3_1, PW1, PW0, b2p_0, b2p_1, bp1, bp0);

    // layer 0
    proj_gemm_kernel<1, true><<<NNODES / 64, 256, 0, stream>>>(x, PW0, bp0, UV);
    edge_mfma_kernel<true><<<NNODES / 4, 512, 0, stream>>>(UV, src, PB2_0, b2p_0, PB3_0, l0_b3, h0b);
    // layer 1
    proj_gemm_kernel<4, false><<<NNODES / 64, 256, 0, stream>>>(h0b, PW1, bp1, UV);
    edge_mfma_kernel<false><<<NNODES / 4, 512, 0, stream>>>(UV, src, PB2_1, b2p_1, PB3_1, l1_b3, h1);
    // pooling + head
    pool1_kernel<<<200, 128, 0, stream>>>(h1, part);
    final_kernel<<<1, 256, 0, stream>>>(part, lin_W1, lin_b1, lin_W2, lin_b2, lin_W3, lin_b3, out);
}

// Round 8
// 439.461 us; speedup vs baseline: 7.7049x; 1.0106x over previous
//
#include <hip/hip_runtime.h>

#define NNODES 25600
#define DEG 16
#define BGRAPHS 8
#define NPG (NNODES / BGRAPHS)   // 3200
#define FDIM 7
#define HDIM 300
#define LDIM 100
#define HP 320                   // padded H
#define UVW 640                  // UV row width (U 0..319 | V 320..639)
#define NT1 20                   // GEMM1 N tiles
#define KS1 10                   // GEMM1 K steps
#define NT2 7                    // GEMM2 N tiles (112 cols, >=100 masked)
#define KS2 10                   // GEMM2 K steps
#define H0W 128                  // h0 fp16 padded width
#define SSTR 328                 // proj staging row stride (shorts)

typedef __attribute__((ext_vector_type(8))) _Float16 half8;
typedef __attribute__((ext_vector_type(2))) _Float16 half2v;
typedef __attribute__((ext_vector_type(4))) float floatx4;

__device__ __forceinline__ unsigned short f2h(float f) {   // fp32 -> fp16 bits (RNE)
    _Float16 h = (_Float16)f;
    return __builtin_bit_cast(unsigned short, h);
}

union UV4H { uint4 v; half2v h[4]; };

// ---------------------------------------------------------------------------
// B-fragment packing: out[((nt*KS+ks)*64+lane)*8+j] = W[k][n]  (fp16 bits)
// ---------------------------------------------------------------------------
__device__ __forceinline__ unsigned short packB(const float* W, int Kreal, int Nreal,
                                                int KS, int rel)
{
    int j = rel & 7, lane = (rel >> 3) & 63, rem = rel >> 9;
    int ks = rem % KS, nt = rem / KS;
    int k = ks * 32 + ((lane >> 4) << 3) + j;
    int n = nt * 16 + (lane & 15);
    float v = (k < Kreal && n < Nreal) ? W[k * Nreal + n] : 0.f;
    return f2h(v);
}

// proj effective weights Weff[k][n], n<320 = U part (W1a - W1b), n>=320 = V part (W1b)
__device__ __forceinline__ unsigned short packProjW(const float* W1, int Ksub,
                                                    int KS, int rel)
{
    int j = rel & 7, lane = (rel >> 3) & 63, rem = rel >> 9;
    int ks = rem % KS, nt = rem / KS;
    int k = ks * 32 + ((lane >> 4) << 3) + j;
    int n = nt * 16 + (lane & 15);
    float v = 0.f;
    if (k < Ksub) {
        if (n < HP) { if (n < HDIM) v = W1[k * HDIM + n] - W1[(k + Ksub) * HDIM + n]; }
        else { int m = n - HP; if (m < HDIM) v = W1[(k + Ksub) * HDIM + m]; }
    }
    return f2h(v);
}

#define S0 102400   // PB2_0
#define S1 102400   // PB2_1
#define S2 35840    // PB3_0
#define S3 35840    // PB3_1
#define S4 81920    // PW1 (40 nt x 4 ks)
#define S5 20480    // PW0 (40 nt x 1 ks)
#define S6 1920     // biases
#define PACK_TOTAL (S0+S1+S2+S3+S4+S5+S6)

__global__ __launch_bounds__(256) void pack_all_kernel(
    const float* __restrict__ l0_W1, const float* __restrict__ l0_b1,
    const float* __restrict__ l0_W2, const float* __restrict__ l0_b2,
    const float* __restrict__ l0_W3,
    const float* __restrict__ l1_W1, const float* __restrict__ l1_b1,
    const float* __restrict__ l1_W2, const float* __restrict__ l1_b2,
    const float* __restrict__ l1_W3,
    unsigned short* __restrict__ PB2_0, unsigned short* __restrict__ PB2_1,
    unsigned short* __restrict__ PB3_0, unsigned short* __restrict__ PB3_1,
    unsigned short* __restrict__ PW1,  unsigned short* __restrict__ PW0,
    float* __restrict__ b2p_0, float* __restrict__ b2p_1,
    float* __restrict__ bp1,   float* __restrict__ bp0)
{
    int idx = blockIdx.x * 256 + threadIdx.x;
    if (idx >= PACK_TOTAL) return;
    if (idx < S0) { PB2_0[idx] = packB(l0_W2, HDIM, HDIM, KS1, idx); return; }
    idx -= S0;
    if (idx < S1) { PB2_1[idx] = packB(l1_W2, HDIM, HDIM, KS1, idx); return; }
    idx -= S1;
    if (idx < S2) { PB3_0[idx] = packB(l0_W3, HDIM, LDIM, KS2, idx); return; }
    idx -= S2;
    if (idx < S3) { PB3_1[idx] = packB(l1_W3, HDIM, LDIM, KS2, idx); return; }
    idx -= S3;
    if (idx < S4) { PW1[idx] = packProjW(l1_W1, LDIM, 4, idx); return; }
    idx -= S4;
    if (idx < S5) { PW0[idx] = packProjW(l0_W1, FDIM, 1, idx); return; }
    idx -= S5;
    if (idx < 320)       { b2p_0[idx] = (idx < HDIM) ? l0_b2[idx] : 0.f; return; }
    if (idx < 640)       { int n = idx - 320; b2p_1[n] = (n < HDIM) ? l1_b2[n] : 0.f; return; }
    if (idx < 1280)      { int n = idx - 640; bp1[n] = (n < HDIM) ? l1_b1[n] : 0.f; return; }
    { int n = idx - 1280; bp0[n] = (n < HDIM) ? l0_b1[n] : 0.f; }
}

// ---------------------------------------------------------------------------
// proj GEMM: A[64 rows] x Weff[K,640] -> UV fp16 [N,640] (bias added, no relu).
// ---------------------------------------------------------------------------
template<int KS, bool A_IS_X>
__global__ __launch_bounds__(256) void proj_gemm_kernel(
    const void* __restrict__ Asrc, const unsigned short* __restrict__ PW,
    const float* __restrict__ bp,
    unsigned short* __restrict__ UV)
{
    __shared__ unsigned short As[4 * KS * 64 * 8];
    __shared__ unsigned short S[64 * SSTR];
    const int t = threadIdx.x;
    const int row0 = blockIdx.x * 64;

    if constexpr (A_IS_X) {
        const float* x = (const float*)Asrc;
        int lane = t & 63, mt = t >> 6;
        int quad = lane >> 4;
        int grow = row0 + mt * 16 + (lane & 15);
        unsigned short oz[8];
#pragma unroll
        for (int j = 0; j < 8; ++j) {
            int k = quad * 8 + j;
            oz[j] = (k < FDIM) ? f2h(x[grow * FDIM + k]) : (unsigned short)0;
        }
        *(uint4*)(As + t * 8) = *(uint4*)oz;
    } else {
        const unsigned short* h = (const unsigned short*)Asrc;
#pragma unroll
        for (int i = 0; i < 4; ++i) {
            int s = t + 256 * i;
            int lane = s & 63;
            int ks = (s >> 6) % KS;
            int mt = s / (KS * 64);
            int grow = row0 + mt * 16 + (lane & 15);
            int k0 = ks * 32 + ((lane >> 4) << 3);
            *(uint4*)(As + s * 8) = *(const uint4*)(h + (size_t)grow * H0W + k0);
        }
    }
    __syncthreads();

    const int w = t >> 6, lane = t & 63, quad = lane >> 4, l15 = lane & 15;

    for (int g = 0; g < 2; ++g) {
        const int ntb = g * 20 + w * 5;
        floatx4 c[5][4];
#pragma unroll
        for (int i = 0; i < 5; ++i)
#pragma unroll
            for (int mt = 0; mt < 4; ++mt) c[i][mt] = (floatx4){0.f, 0.f, 0.f, 0.f};
#pragma unroll
        for (int ks = 0; ks < KS; ++ks) {
            half8 a[4];
#pragma unroll
            for (int mt = 0; mt < 4; ++mt)
                a[mt] = *(const half8*)(As + ((mt * KS + ks) * 64 + lane) * 8);
#pragma unroll
            for (int i = 0; i < 5; ++i) {
                half8 b = *(const half8*)(PW + (size_t)(((ntb + i) * KS + ks) * 64 + lane) * 8);
#pragma unroll
                for (int mt = 0; mt < 4; ++mt)
                    c[i][mt] = __builtin_amdgcn_mfma_f32_16x16x32_f16(a[mt], b, c[i][mt], 0, 0, 0);
            }
        }
        __syncthreads();   // prev group's readout complete before overwriting S
#pragma unroll
        for (int i = 0; i < 5; ++i) {
            int colp = (w * 5 + i) * 16 + l15;        // 0..319 group-local
            float bb = bp[g * 320 + colp];
#pragma unroll
            for (int mt = 0; mt < 4; ++mt) {
#pragma unroll
                for (int r = 0; r < 4; ++r) {
                    int row = mt * 16 + quad * 4 + r;
                    S[row * SSTR + colp] = f2h(c[i][mt][r] + bb);
                }
            }
        }
        __syncthreads();
#pragma unroll
        for (int it = 0; it < 10; ++it) {
            int s = t + 256 * it;
            int row = s / 40, c4 = s - row * 40;
            uint4 v = *(const uint4*)(S + row * SSTR + c4 * 8);
            *(uint4*)(UV + (size_t)(row0 + row) * UVW + g * 320 + c4 * 8) = v;
        }
    }
}

// ---------------------------------------------------------------------------
// Fused edge MLP + segment-max. Block = 4 nodes (M=64), 512 threads / 8 waves.
// fp16 pipeline: Z1 = relu(U+V) via packed v_pk_add_f16/v_pk_max_f16 (2 VALU
// ops per dword vs ~7 for bf16 emulation). Single 40 KB LDS buffer, 3 barriers.
//   GEMM1: wave owns {3,3,3,3,2,2,2,2} ntiles -> C1 regs <= 48
//   GEMM2: wave w<7 owns 1 ntile             -> C2 regs = 16
// ---------------------------------------------------------------------------
template<bool OUT_HALF>
__global__ __launch_bounds__(512, 4) void edge_mfma_kernel(
    const unsigned short* __restrict__ UV,
    const int* __restrict__ src,
    const unsigned short* __restrict__ PB2, const float* __restrict__ b2p,
    const unsigned short* __restrict__ PB3, const float* __restrict__ b3,
    void* __restrict__ hout)
{
    __shared__ unsigned short Zs[4 * KS1 * 64 * 8];   // 40960 B, Z1 then Z2

    const int t = threadIdx.x;
    const int node0 = blockIdx.x * 4;
    const int lane = t & 63;
    const int w = t >> 6;                 // 0..7
    const int quad = lane >> 4;
    const int l15 = lane & 15;
    const int slane = lane ^ ((lane & 0x30) >> 3);   // sigma(lane) for Z1 reads

    // Z1-build lane mapping (64B-coalesced gather + swizzled LDS dest)
    const int row16 = lane >> 2;          // 0..15
    const int part  = lane & 3;           // 0..3
    const int fl    = row16 + 16 * part;  // A-frag lane
    const int phys  = fl ^ (part << 1);   // sigma(fl)

    const half2v hzero = {(_Float16)0.f, (_Float16)0.f};

    // ---- Z1 build: 2560 slots, 5 per thread, packed fp16 math ----
#pragma unroll
    for (int i = 0; i < 5; ++i) {
        int s = t + 512 * i;
        int ks = (s >> 6) % KS1;
        int mt = s / (KS1 * 64);
        int m = mt * 16 + row16;
        int k0 = ks * 32 + part * 8;
        int srcn = src[node0 * 16 + m];
        UV4H ud, vd, o;
        ud.v = *(const uint4*)(UV + (size_t)(node0 + mt) * UVW + k0);
        vd.v = *(const uint4*)(UV + (size_t)srcn * UVW + HP + k0);
#pragma unroll
        for (int d = 0; d < 4; ++d) {
            half2v s2 = ud.h[d] + vd.h[d];                       // v_pk_add_f16
            o.h[d] = __builtin_elementwise_max(s2, hzero);       // v_pk_max_f16
        }
        *(uint4*)(Zs + ((mt * KS1 + ks) * 64 + phys) * 8) = o.v;
    }
    __syncthreads();

    // ---- GEMM1: wave owns cnt1 ntiles starting at base1, all 4 mt ----
    const int cnt1  = (w < 4) ? 3 : 2;
    const int base1 = (w < 4) ? 3 * w : 12 + 2 * (w - 4);
    floatx4 c1[3][4];
#pragma unroll
    for (int i = 0; i < 3; ++i)
#pragma unroll
        for (int mt = 0; mt < 4; ++mt) c1[i][mt] = (floatx4){0.f, 0.f, 0.f, 0.f};
    for (int ks = 0; ks < KS1; ++ks) {
        half8 a[4];
#pragma unroll
        for (int mt = 0; mt < 4; ++mt)
            a[mt] = *(const half8*)(Zs + ((mt * KS1 + ks) * 64 + slane) * 8);
#pragma unroll
        for (int i = 0; i < 3; ++i) {
            if (i < cnt1) {
                half8 b = *(const half8*)(PB2 + (size_t)(((base1 + i) * KS1 + ks) * 64 + lane) * 8);
#pragma unroll
                for (int mt = 0; mt < 4; ++mt)
                    c1[i][mt] = __builtin_amdgcn_mfma_f32_16x16x32_f16(a[mt], b, c1[i][mt], 0, 0, 0);
            }
        }
    }
    __syncthreads();   // all waves done reading Z1

    // ---- Z2 scatter into Zs (A-frag order, identity), +b2, relu ----
#pragma unroll
    for (int i = 0; i < 3; ++i) {
        if (i < cnt1) {
            int col = (base1 + i) * 16 + l15;            // 0..319
            float b2v = b2p[col];
            int slotbase = (col >> 5) * 64 + (((col >> 3) & 3) << 4) + quad * 4;
            int j = col & 7;
#pragma unroll
            for (int mt = 0; mt < 4; ++mt) {
#pragma unroll
                for (int r = 0; r < 4; ++r) {
                    float v = fmaxf(c1[i][mt][r] + b2v, 0.f);
                    Zs[(mt * KS1 * 64 + slotbase + r) * 8 + j] = f2h(v);
                }
            }
        }
    }
    __syncthreads();

    // ---- GEMM2: wave w<7 owns ntile w, all 4 mt ----
    floatx4 c2[4];
#pragma unroll
    for (int mt = 0; mt < 4; ++mt) c2[mt] = (floatx4){0.f, 0.f, 0.f, 0.f};
    if (w < NT2) {
        for (int ks = 0; ks < KS2; ++ks) {
            half8 a[4];
#pragma unroll
            for (int mt = 0; mt < 4; ++mt)
                a[mt] = *(const half8*)(Zs + ((mt * KS2 + ks) * 64 + lane) * 8);
            half8 b = *(const half8*)(PB3 + (size_t)((w * KS2 + ks) * 64 + lane) * 8);
#pragma unroll
            for (int mt = 0; mt < 4; ++mt)
                c2[mt] = __builtin_amdgcn_mfma_f32_16x16x32_f16(a[mt], b, c2[mt], 0, 0, 0);
        }
    }

    // ---- epilogue: max over 16 edge rows, +b3, relu, store ----
#pragma unroll
    for (int mt = 0; mt < 4; ++mt) {
        int node = node0 + mt;
        if (w < NT2) {
            int col = w * 16 + l15;
            floatx4 a = c2[mt];
            float mx = fmaxf(fmaxf(a[0], a[1]), fmaxf(a[2], a[3]));
            mx = fmaxf(mx, __shfl_xor(mx, 16, 64));
            mx = fmaxf(mx, __shfl_xor(mx, 32, 64));
            if (quad == 0) {
                if (OUT_HALF) {
                    unsigned short val = 0;
                    if (col < LDIM) val = f2h(fmaxf(mx + b3[col], 0.f));
                    ((unsigned short*)hout)[(size_t)node * H0W + col] = val;
                } else {
                    if (col < LDIM)
                        ((float*)hout)[(size_t)node * LDIM + col] = fmaxf(mx + b3[col], 0.f);
                }
            }
        }
        if (OUT_HALF && w == 7 && quad == 0)     // pad cols 112..127
            ((unsigned short*)hout)[(size_t)node * H0W + 112 + l15] = 0;
    }
}

// ---------------------------------------------------------------------------
__global__ __launch_bounds__(128) void pool1_kernel(
    const float* __restrict__ h, float* __restrict__ part)
{
    int g = blockIdx.x / 25;
    int sl = blockIdx.x % 25;
    int t = threadIdx.x;
    int base = g * NPG + sl * 128;
    if (t < LDIM) {
        float s = 0.f, mx = -1e30f;
        for (int i = 0; i < 128; ++i) {
            float v = h[(size_t)(base + i) * LDIM + t];
            s += v;
            mx = fmaxf(mx, v);
        }
        part[(size_t)blockIdx.x * 200 + t] = s;
        part[(size_t)blockIdx.x * 200 + 100 + t] = mx;
    }
}

__global__ __launch_bounds__(256) void final_kernel(
    const float* __restrict__ part,
    const float* __restrict__ W1, const float* __restrict__ b1,
    const float* __restrict__ W2, const float* __restrict__ b2,
    const float* __restrict__ W3, const float* __restrict__ b3,
    float* __restrict__ out)
{
    __shared__ float P[BGRAPHS][3 * LDIM];
    __shared__ float T1[BGRAPHS][LDIM];
    __shared__ float T2[BGRAPHS][LDIM];
    int t = threadIdx.x;
    for (int i = t; i < BGRAPHS * LDIM; i += 256) {
        int g = i / LDIM, f = i - (i / LDIM) * LDIM;
        float s = 0.f, mx = -1e30f;
        for (int sl = 0; sl < 25; ++sl) {
            s += part[(size_t)(g * 25 + sl) * 200 + f];
            mx = fmaxf(mx, part[(size_t)(g * 25 + sl) * 200 + 100 + f]);
        }
        P[g][f] = s;
        P[g][LDIM + f] = s * (1.0f / NPG);
        P[g][2 * LDIM + f] = mx;
    }
    __syncthreads();
    for (int i = t; i < BGRAPHS * LDIM; i += 256) {
        int g = i / LDIM, c = i - (i / LDIM) * LDIM;
        float a = b1[c];
        for (int k = 0; k < 3 * LDIM; ++k) a = fmaf(P[g][k], W1[k * LDIM + c], a);
        T1[g][c] = fmaxf(a, 0.f);
    }
    __syncthreads();
    for (int i = t; i < BGRAPHS * LDIM; i += 256) {
        int g = i / LDIM, c = i - (i / LDIM) * LDIM;
        float a = b2[c];
        for (int k = 0; k < LDIM; ++k) a = fmaf(T1[g][k], W2[k * LDIM + c], a);
        T2[g][c] = fmaxf(a, 0.f);
    }
    __syncthreads();
    if (t < BGRAPHS) {
        float a = b3[0];
        for (int k = 0; k < LDIM; ++k) a = fmaf(T2[t][k], W3[k], a);
        out[t] = a;
    }
}

// ---------------------------------------------------------------------------
extern "C" void kernel_launch(void* const* d_in, const int* in_sizes, int n_in,
                              void* d_out, int out_size, void* d_ws, size_t ws_size,
                              hipStream_t stream)
{
    const float* x      = (const float*)d_in[0];
    const int*   src    = (const int*)d_in[1];
    const float* l0_W1  = (const float*)d_in[3];
    const float* l0_b1  = (const float*)d_in[4];
    const float* l0_W2  = (const float*)d_in[5];
    const float* l0_b2  = (const float*)d_in[6];
    const float* l0_W3  = (const float*)d_in[7];
    const float* l0_b3  = (const float*)d_in[8];
    const float* l1_W1  = (const float*)d_in[9];
    const float* l1_b1  = (const float*)d_in[10];
    const float* l1_W2  = (const float*)d_in[11];
    const float* l1_b2  = (const float*)d_in[12];
    const float* l1_W3  = (const float*)d_in[13];
    const float* l1_b3  = (const float*)d_in[14];
    const float* lin_W1 = (const float*)d_in[15];
    const float* lin_b1 = (const float*)d_in[16];
    const float* lin_W2 = (const float*)d_in[17];
    const float* lin_b2 = (const float*)d_in[18];
    const float* lin_W3 = (const float*)d_in[19];
    const float* lin_b3 = (const float*)d_in[20];
    float* out = (float*)d_out;

    char* p = (char*)d_ws;
    unsigned short* UV    = (unsigned short*)p;  p += (size_t)NNODES * UVW * 2;     // 32.77 MB
    unsigned short* h0b   = (unsigned short*)p;  p += (size_t)NNODES * H0W * 2;     // 6.55 MB
    float* h1             = (float*)p;           p += (size_t)NNODES * LDIM * 4;    // 10.24 MB
    unsigned short* PB2_0 = (unsigned short*)p;  p += (size_t)S0 * 2;
    unsigned short* PB2_1 = (unsigned short*)p;  p += (size_t)S1 * 2;
    unsigned short* PB3_0 = (unsigned short*)p;  p += (size_t)S2 * 2;
    unsigned short* PB3_1 = (unsigned short*)p;  p += (size_t)S3 * 2;
    unsigned short* PW1   = (unsigned short*)p;  p += (size_t)S4 * 2;
    unsigned short* PW0   = (unsigned short*)p;  p += (size_t)S5 * 2;
    float* b2p_0          = (float*)p;           p += HP * 4;
    float* b2p_1          = (float*)p;           p += HP * 4;
    float* bp1            = (float*)p;           p += 640 * 4;
    float* bp0            = (float*)p;           p += 640 * 4;
    float* part           = (float*)p;           p += (size_t)200 * 200 * 4;

    pack_all_kernel<<<(PACK_TOTAL + 255) / 256, 256, 0, stream>>>(
        l0_W1, l0_b1, l0_W2, l0_b2, l0_W3,
        l1_W1, l1_b1, l1_W2, l1_b2, l1_W3,
        PB2_0, PB2_1, PB3_0, PB3_1, PW1, PW0, b2p_0, b2p_1, bp1, bp0);

    // layer 0
    proj_gemm_kernel<1, true><<<NNODES / 64, 256, 0, stream>>>(x, PW0, bp0, UV);
    edge_mfma_kernel<true><<<NNODES / 4, 512, 0, stream>>>(UV, src, PB2_0, b2p_0, PB3_0, l0_b3, h0b);
    // layer 1
    proj_gemm_kernel<4, false><<<NNODES / 64, 256, 0, stream>>>(h0b, PW1, bp1, UV);
    edge_mfma_kernel<false><<<NNODES / 4, 512, 0, stream>>>(UV, src, PB2_1, b2p_1, PB3_1, l1_b3, h1);
    // pooling + head
    pool1_kernel<<<200, 128, 0, stream>>>(h1, part);
    final_kernel<<<1, 256, 0, stream>>>(part, lin_W1, lin_b1, lin_W2, lin_b2, lin_W3, lin_b3, out);
}